// Round 6
// baseline (97.406 us; speedup 1.0000x reference)
//
#include <hip/hip_runtime.h>

// Chamfer loss: x [B,N,D], y [B,M,D], D=3, fp32.
// dist[b,m,n] = ||x[b,n]-y[b,m]||^2
// row[b] = mean_n min_m dist ; col[b] = mean_m min_n dist
// out = mean_b max(row, col)
//
// R6: revert to R4's measured-best K1 (launch_bounds(256,8) matters: 64-VGPR
// cap -> 8 blocks/CU -> 8 waves/SIMD hides LDS/global latency; removing it
// in R5 cost ~10 us). Keep R5's merged combine+finalize (2 dispatches total).
//  K1: 2048 blocks (2 dir x 32 batch x 32 chunks), 256 thr, QPT=8.
//      Register-block 8 queries/thread, scan 64-target LDS chunk,
//      write partial mins [seg][chunk][query]. Block 0 arms done-counter.
//  K2: 512 blocks: min over 32 chunks, finish dist, block sums; last block
//      reduces -> max(row,col) -> mean -> out.

#define BATCH   32
#define NPTS    2048
#define THREADS 256
#define QPT     8              // 256*8 = 2048 queries per block
#define TCH     32             // target chunks per (dir,batch)
#define TC      (NPTS / TCH)   // 64 targets per chunk
#define NSEG    (2 * BATCH)    // 64 segments
#define CBLK    8              // combine blocks per segment
#define NCOMB   (NSEG * CBLK)  // 512 combine blocks

__global__ __launch_bounds__(THREADS, 8) void chamfer_min(
    const float* __restrict__ x, const float* __restrict__ y,
    float* __restrict__ part /* [NSEG][TCH][NPTS] */,
    unsigned* __restrict__ done)
{
    __shared__ float4 t4[TC];   // (tx,ty,tz, 0.5*||t||^2) — 1 KB

    const int blk   = blockIdx.x;      // 2048
    const int dir   = blk >> 10;
    const int r     = blk & 1023;
    const int b     = r >> 5;
    const int chunk = r & 31;

    if (blk == 0 && threadIdx.x == 0) *done = 0u;   // arm K2's counter

    const float* q = (dir == 0 ? x : y) + (size_t)b * NPTS * 3;
    const float* t = (dir == 0 ? y : x) + (size_t)b * NPTS * 3;

    // Stage this chunk's 64 targets with precomputed h = 0.5*||t||^2.
    if (threadIdx.x < TC) {
        int jj = chunk * TC + threadIdx.x;
        float tx = t[3 * jj + 0];
        float ty = t[3 * jj + 1];
        float tz = t[3 * jj + 2];
        t4[threadIdx.x] = make_float4(tx, ty, tz, 0.5f * (tx * tx + ty * ty + tz * tz));
    }

    // 8 query points per thread (covers all 2048 queries per block).
    float qx[QPT], qy[QPT], qz[QPT], mn[QPT];
#pragma unroll
    for (int k = 0; k < QPT; ++k) {
        int qi = threadIdx.x + k * THREADS;
        qx[k] = q[3 * qi + 0];
        qy[k] = q[3 * qi + 1];
        qz[k] = q[3 * qi + 2];
        mn[k] = 3.4e38f;
    }
    __syncthreads();

    // min over chunk targets of s = h_t - q.t  (dist = 2s + ||q||^2, monotone)
#pragma unroll 4
    for (int j = 0; j < TC; j += 2) {
        float4 a = t4[j];
        float4 c = t4[j + 1];
#pragma unroll
        for (int k = 0; k < QPT; ++k) {
            float s0 = fmaf(-qz[k], a.z, fmaf(-qy[k], a.y, fmaf(-qx[k], a.x, a.w)));
            float s1 = fmaf(-qz[k], c.z, fmaf(-qy[k], c.y, fmaf(-qx[k], c.x, c.w)));
            mn[k] = fminf(fminf(mn[k], s0), s1);   // v_min3_f32
        }
    }

    // Plain coalesced partial writes — no init, no atomics.
    float* pbase = part + ((size_t)(dir * BATCH + b) * TCH + chunk) * NPTS;
#pragma unroll
    for (int k = 0; k < QPT; ++k)
        pbase[threadIdx.x + k * THREADS] = mn[k];
}

__global__ __launch_bounds__(THREADS) void chamfer_combine(
    const float* __restrict__ x, const float* __restrict__ y,
    const float* __restrict__ part,
    float* __restrict__ blocksums /* [NCOMB] */,
    unsigned* __restrict__ done,
    float* __restrict__ out)
{
    __shared__ float wsum[THREADS / 64];
    __shared__ int flagLast;

    const int blk = blockIdx.x;        // 512 = NSEG * CBLK
    const int seg = blk >> 3;
    const int qc  = blk & 7;
    const int dir = seg >> 5;
    const int b   = seg & 31;
    const int qi  = qc * THREADS + threadIdx.x;

    // min over the 32 chunk partials (wave-coalesced strided loads)
    const float* p = part + (size_t)seg * TCH * NPTS + qi;
    float mn = p[0];
#pragma unroll
    for (int c = 1; c < TCH; ++c)
        mn = fminf(mn, p[(size_t)c * NPTS]);

    const float* q = (dir == 0 ? x : y) + (size_t)b * NPTS * 3 + 3 * qi;
    float qx = q[0], qy = q[1], qz = q[2];
    float d = fmaf(2.0f, mn, qx * qx + qy * qy + qz * qz);

    for (int off = 32; off > 0; off >>= 1)
        d += __shfl_down(d, off);
    if ((threadIdx.x & 63) == 0) wsum[threadIdx.x >> 6] = d;
    __syncthreads();

    if (threadIdx.x == 0) {
        float tot = wsum[0] + wsum[1] + wsum[2] + wsum[3];
        __hip_atomic_store(&blocksums[blk], tot, __ATOMIC_RELEASE,
                           __HIP_MEMORY_SCOPE_AGENT);
        unsigned old = __hip_atomic_fetch_add(done, 1u, __ATOMIC_ACQ_REL,
                                              __HIP_MEMORY_SCOPE_AGENT);
        flagLast = (old == (unsigned)(NCOMB - 1));
    }
    __syncthreads();
    if (!flagLast) return;

    // ---- last block: per-seg totals, max(row,col), mean ----
    if (threadIdx.x < 64) {
        const int lane = threadIdx.x;   // lane = seg
        float s = 0.0f;
#pragma unroll
        for (int i = 0; i < CBLK; ++i)
            s += __hip_atomic_load(&blocksums[lane * CBLK + i],
                                   __ATOMIC_ACQUIRE, __HIP_MEMORY_SCOPE_AGENT);
        // lane < 32: row(batch=lane) ; lane >= 32: col(batch=lane-32)
        float other = __shfl(s, lane + 32);
        float v = (lane < 32) ? fmaxf(s, other) * (1.0f / NPTS) : 0.0f;
        for (int off = 16; off > 0; off >>= 1)
            v += __shfl_down(v, off);
        if (lane == 0) out[0] = v * (1.0f / BATCH);
    }
}

extern "C" void kernel_launch(void* const* d_in, const int* in_sizes, int n_in,
                              void* d_out, int out_size, void* d_ws, size_t ws_size,
                              hipStream_t stream) {
    const float* x = (const float*)d_in[0];
    const float* y = (const float*)d_in[1];
    float* out = (float*)d_out;

    float*    part      = (float*)d_ws;                          // 16 MB
    float*    blocksums = part + (size_t)NSEG * TCH * NPTS;      // 2 KB
    unsigned* done      = (unsigned*)(blocksums + NCOMB);

    chamfer_min<<<2 * BATCH * TCH, THREADS, 0, stream>>>(x, y, part, done);
    chamfer_combine<<<NCOMB, THREADS, 0, stream>>>(x, y, part, blocksums, done, out);
}

// Round 8
// 96.779 us; speedup vs baseline: 1.0065x; 1.0065x over previous
//
#include <hip/hip_runtime.h>

// Chamfer loss: x [B,N,D], y [B,M,D], D=3, fp32.
// dist[b,m,n] = ||x[b,n]-y[b,m]||^2
// row[b] = mean_n min_m dist ; col[b] = mean_m min_n dist
// out = mean_b max(row, col)
//
// R7 (resubmit; R7 bench was a GPU-acquisition timeout): packed-fp32 inner
// loop. LDS target tile stored SoA (X,Y,Z,H), read as float4 quads; two
// targets per v_pk_fma_f32. Per quad per query: 6 pk_fma + 2 min3
// = 2.0 VALU ops/pair (was 3.5). Everything else = R6:
//  K1: 2048 blocks (2 dir x 32 batch x 32 chunks), 256 thr, QPT=8,
//      partial mins -> part[seg][chunk][query]; block 0 arms done counter.
//  K2: 512 blocks: min over 32 chunks, finish dist, block sums; last block
//      reduces -> max(row,col) -> mean -> out.

#define BATCH   32
#define NPTS    2048
#define THREADS 256
#define QPT     8              // 256*8 = 2048 queries per block
#define TCH     32             // target chunks per (dir,batch)
#define TC      (NPTS / TCH)   // 64 targets per chunk
#define NSEG    (2 * BATCH)    // 64 segments
#define CBLK    8              // combine blocks per segment
#define NCOMB   (NSEG * CBLK)  // 512 combine blocks

typedef float v2f __attribute__((ext_vector_type(2)));
typedef float v4f __attribute__((ext_vector_type(4)));

__global__ __launch_bounds__(THREADS) void chamfer_min(
    const float* __restrict__ x, const float* __restrict__ y,
    float* __restrict__ part /* [NSEG][TCH][NPTS] */,
    unsigned* __restrict__ done)
{
    // SoA target tile: X, Y, Z, H rows of 64 floats (16B-aligned rows).
    __shared__ __align__(16) float lds[4][TC];

    const int blk   = blockIdx.x;      // 2048
    const int dir   = blk >> 10;
    const int r     = blk & 1023;
    const int b     = r >> 5;
    const int chunk = r & 31;

    if (blk == 0 && threadIdx.x == 0) *done = 0u;   // arm K2's counter

    const float* q = (dir == 0 ? x : y) + (size_t)b * NPTS * 3;
    const float* t = (dir == 0 ? y : x) + (size_t)b * NPTS * 3;

    // Stage this chunk's 64 targets SoA with h = 0.5*||t||^2.
    if (threadIdx.x < TC) {
        int jj = chunk * TC + threadIdx.x;
        float tx = t[3 * jj + 0];
        float ty = t[3 * jj + 1];
        float tz = t[3 * jj + 2];
        lds[0][threadIdx.x] = tx;
        lds[1][threadIdx.x] = ty;
        lds[2][threadIdx.x] = tz;
        lds[3][threadIdx.x] = 0.5f * (tx * tx + ty * ty + tz * tz);
    }

    // 8 query points per thread, pre-packed as {-q,-q} for pk_fma.
    v2f nqx[QPT], nqy[QPT], nqz[QPT];
    float mn[QPT];
#pragma unroll
    for (int k = 0; k < QPT; ++k) {
        int qi = threadIdx.x + k * THREADS;
        float qx = q[3 * qi + 0];
        float qy = q[3 * qi + 1];
        float qz = q[3 * qi + 2];
        nqx[k] = (v2f){-qx, -qx};
        nqy[k] = (v2f){-qy, -qy};
        nqz[k] = (v2f){-qz, -qz};
        mn[k] = 3.4e38f;
    }
    __syncthreads();

    // min over chunk targets of s = h_t - q.t  (dist = 2s + ||q||^2, monotone).
    // Quad of targets per iteration: 4 broadcast ds_read_b128, halves are v2f.
#pragma unroll 2
    for (int p = 0; p < TC / 4; ++p) {
        v4f X = *(const v4f*)&lds[0][4 * p];
        v4f Y = *(const v4f*)&lds[1][4 * p];
        v4f Z = *(const v4f*)&lds[2][4 * p];
        v4f H = *(const v4f*)&lds[3][4 * p];
        v2f xlo = X.lo, xhi = X.hi;
        v2f ylo = Y.lo, yhi = Y.hi;
        v2f zlo = Z.lo, zhi = Z.hi;
        v2f hlo = H.lo, hhi = H.hi;
#pragma unroll
        for (int k = 0; k < QPT; ++k) {
            v2f s01 = __builtin_elementwise_fma(nqz[k], zlo,
                      __builtin_elementwise_fma(nqy[k], ylo,
                      __builtin_elementwise_fma(nqx[k], xlo, hlo)));
            v2f s23 = __builtin_elementwise_fma(nqz[k], zhi,
                      __builtin_elementwise_fma(nqy[k], yhi,
                      __builtin_elementwise_fma(nqx[k], xhi, hhi)));
            mn[k] = fminf(fminf(mn[k], s01.x), s01.y);   // v_min3_f32
            mn[k] = fminf(fminf(mn[k], s23.x), s23.y);   // v_min3_f32
        }
    }

    // Plain coalesced partial writes — no init, no atomics.
    float* pbase = part + ((size_t)(dir * BATCH + b) * TCH + chunk) * NPTS;
#pragma unroll
    for (int k = 0; k < QPT; ++k)
        pbase[threadIdx.x + k * THREADS] = mn[k];
}

__global__ __launch_bounds__(THREADS) void chamfer_combine(
    const float* __restrict__ x, const float* __restrict__ y,
    const float* __restrict__ part,
    float* __restrict__ blocksums /* [NCOMB] */,
    unsigned* __restrict__ done,
    float* __restrict__ out)
{
    __shared__ float wsum[THREADS / 64];
    __shared__ int flagLast;

    const int blk = blockIdx.x;        // 512 = NSEG * CBLK
    const int seg = blk >> 3;
    const int qc  = blk & 7;
    const int dir = seg >> 5;
    const int b   = seg & 31;
    const int qi  = qc * THREADS + threadIdx.x;

    // min over the 32 chunk partials (wave-coalesced strided loads)
    const float* p = part + (size_t)seg * TCH * NPTS + qi;
    float mn = p[0];
#pragma unroll
    for (int c = 1; c < TCH; ++c)
        mn = fminf(mn, p[(size_t)c * NPTS]);

    const float* q = (dir == 0 ? x : y) + (size_t)b * NPTS * 3 + 3 * qi;
    float qx = q[0], qy = q[1], qz = q[2];
    float d = fmaf(2.0f, mn, qx * qx + qy * qy + qz * qz);

    for (int off = 32; off > 0; off >>= 1)
        d += __shfl_down(d, off);
    if ((threadIdx.x & 63) == 0) wsum[threadIdx.x >> 6] = d;
    __syncthreads();

    if (threadIdx.x == 0) {
        float tot = wsum[0] + wsum[1] + wsum[2] + wsum[3];
        __hip_atomic_store(&blocksums[blk], tot, __ATOMIC_RELEASE,
                           __HIP_MEMORY_SCOPE_AGENT);
        unsigned old = __hip_atomic_fetch_add(done, 1u, __ATOMIC_ACQ_REL,
                                              __HIP_MEMORY_SCOPE_AGENT);
        flagLast = (old == (unsigned)(NCOMB - 1));
    }
    __syncthreads();
    if (!flagLast) return;

    // ---- last block: per-seg totals, max(row,col), mean ----
    if (threadIdx.x < 64) {
        const int lane = threadIdx.x;   // lane = seg
        float s = 0.0f;
#pragma unroll
        for (int i = 0; i < CBLK; ++i)
            s += __hip_atomic_load(&blocksums[lane * CBLK + i],
                                   __ATOMIC_ACQUIRE, __HIP_MEMORY_SCOPE_AGENT);
        // lane < 32: row(batch=lane) ; lane >= 32: col(batch=lane-32)
        float other = __shfl(s, lane + 32);
        float v = (lane < 32) ? fmaxf(s, other) * (1.0f / NPTS) : 0.0f;
        for (int off = 16; off > 0; off >>= 1)
            v += __shfl_down(v, off);
        if (lane == 0) out[0] = v * (1.0f / BATCH);
    }
}

extern "C" void kernel_launch(void* const* d_in, const int* in_sizes, int n_in,
                              void* d_out, int out_size, void* d_ws, size_t ws_size,
                              hipStream_t stream) {
    const float* x = (const float*)d_in[0];
    const float* y = (const float*)d_in[1];
    float* out = (float*)d_out;

    float*    part      = (float*)d_ws;                          // 16 MB
    float*    blocksums = part + (size_t)NSEG * TCH * NPTS;      // 2 KB
    unsigned* done      = (unsigned*)(blocksums + NCOMB);

    chamfer_min<<<2 * BATCH * TCH, THREADS, 0, stream>>>(x, y, part, done);
    chamfer_combine<<<NCOMB, THREADS, 0, stream>>>(x, y, part, blocksums, done, out);
}